// Round 1
// baseline (3389.985 us; speedup 1.0000x reference)
//
#include <hip/hip_runtime.h>
#include <math.h>

#define B_ 2
#define C_ 256
#define FD_ 384
#define K_ 32

// ---------------- weight transpose: wT[c][o] = w[o][c] ----------------
__global__ void k_transpose(const float* __restrict__ w, float* __restrict__ wT, int O, int C) {
    int idx = blockIdx.x * 256 + threadIdx.x;
    if (idx >= O * C) return;
    int o = idx / C, c = idx % C;
    wT[c * O + o] = w[o * C + c];
}

// ---------------- pre_proj: conv1x1 384->256 over 48x80 ----------------
// grid: B*256 blocks (b,o); 256 threads; each thread 15 pixels
__global__ void k_preproj(const float* __restrict__ src, const float* __restrict__ w,
                          float* __restrict__ out) {
    __shared__ float w_s[FD_];
    int bo = blockIdx.x;
    int b = bo >> 8, o = bo & 255;
    int tid = threadIdx.x;
    for (int i = tid; i < FD_; i += 256) w_s[i] = w[o * FD_ + i];
    __syncthreads();
    float acc[15];
#pragma unroll
    for (int k = 0; k < 15; k++) acc[k] = 0.f;
    const float* sp = src + (long)b * FD_ * 3840;
    for (int c = 0; c < FD_; c++) {
        float wv = w_s[c];
        const float* row = sp + (long)c * 3840;
#pragma unroll
        for (int k = 0; k < 15; k++) acc[k] += wv * row[tid + k * 256];
    }
    float* op = out + ((long)b * 256 + o) * 3840;
#pragma unroll
    for (int k = 0; k < 15; k++) op[tid + k * 256] = acc[k];
}

// ---------------- guidance downsample, H axis (tent, antialias) ----------------
// in: [B,3,768,1280] -> out: [B,3,Ho,1280]
__global__ void k_down_h(const float* __restrict__ in, float* __restrict__ out, int Ho, float s) {
    long idx = (long)blockIdx.x * 256 + threadIdx.x;
    long total = (long)B_ * 3 * Ho * 1280;
    if (idx >= total) return;
    int x = (int)(idx % 1280);
    long t1 = idx / 1280;
    int i = (int)(t1 % Ho);
    long t2 = t1 / Ho;
    int c = (int)(t2 % 3);
    int b = (int)(t2 / 3);
    float sf = (i + 0.5f) * s - 0.5f;
    int j0 = (int)floorf(sf - s) + 1;
    int j1 = (int)ceilf(sf + s) - 1;
    float acc = 0.f, wsum = 0.f;
    const float* ip = in + ((long)(b * 3 + c) * 768) * 1280 + x;
    for (int j = j0; j <= j1; j++) {
        if (j < 0 || j >= 768) continue;
        float wv = 1.f - fabsf((float)j - sf) / s;
        acc += wv * ip[(long)j * 1280];
        wsum += wv;
    }
    out[idx] = acc / wsum;
}

// in: [B,3,Ho,1280] -> out: [B,3,Ho,Wo]
__global__ void k_down_w(const float* __restrict__ in, float* __restrict__ out, int Ho, int Wo, float s) {
    long idx = (long)blockIdx.x * 256 + threadIdx.x;
    long total = (long)B_ * 3 * Ho * Wo;
    if (idx >= total) return;
    int i = (int)(idx % Wo);
    long t1 = idx / Wo;
    int y = (int)(t1 % Ho);
    long t2 = t1 / Ho;
    int c = (int)(t2 % 3);
    int b = (int)(t2 / 3);
    float sf = (i + 0.5f) * s - 0.5f;
    int j0 = (int)floorf(sf - s) + 1;
    int j1 = (int)ceilf(sf + s) - 1;
    float acc = 0.f, wsum = 0.f;
    const float* ip = in + ((long)(b * 3 + c) * Ho + y) * 1280;
    for (int j = j0; j <= j1; j++) {
        if (j < 0 || j >= 1280) continue;
        float wv = 1.f - fabsf((float)j - sf) / s;
        acc += wv * ip[j];
        wsum += wv;
    }
    out[idx] = acc / wsum;
}

// ---------------- range projection MLP: g[B,3,H,W] -> proj[B,32,H,W] ----------------
__global__ void k_proj(const float* __restrict__ g, float* __restrict__ proj,
                       const float* __restrict__ w1, const float* __restrict__ b1,
                       const float* __restrict__ w2, const float* __restrict__ b2,
                       int HW) {
    __shared__ float w1_s[96], b1_s[32], w2_s[1024], b2_s[32];
    int tid = threadIdx.x;
    if (tid < 96) w1_s[tid] = w1[tid];
    if (tid < 32) { b1_s[tid] = b1[tid]; b2_s[tid] = b2[tid]; }
    for (int i = tid; i < 1024; i += 256) w2_s[i] = w2[i];
    __syncthreads();
    long idx = (long)blockIdx.x * 256 + tid;
    if (idx >= (long)B_ * HW) return;
    int b = (int)(idx / HW);
    int pix = (int)(idx % HW);
    const float* gp = g + (long)b * 3 * HW + pix;
    float g0 = gp[0], g1 = gp[HW], g2 = gp[2 * (long)HW];
    float hg[32];
#pragma unroll
    for (int k = 0; k < 32; k++) {
        float h = b1_s[k] + w1_s[k * 3] * g0 + w1_s[k * 3 + 1] * g1 + w1_s[k * 3 + 2] * g2;
        hg[k] = 0.5f * h * (1.f + erff(h * 0.70710678118654752f));
    }
    float* pp = proj + (long)b * 32 * HW + pix;
#pragma unroll
    for (int j = 0; j < 32; j++) {
        float a = b2_s[j];
#pragma unroll
        for (int k = 0; k < 32; k++) a += w2_s[j * 32 + k] * hg[k];
        pp[(long)j * HW] = a;
    }
}

// ---------------- sims + softmax + spatial + renorm -> ck[B,49,H,W] ----------------
// block 256 = 16x16 pixel tile; grid (W/16, H/16, B)
__global__ void k_ck(const float* __restrict__ proj, float* __restrict__ ck,
                     const float* __restrict__ temp, const float* __restrict__ sigma,
                     int H, int W) {
    __shared__ float p_s[32 * 22 * 22];
    int tx = threadIdx.x & 15, ty = threadIdx.x >> 4;
    int x0 = blockIdx.x * 16, y0 = blockIdx.y * 16;
    int b = blockIdx.z;
    const float* pb = proj + (long)b * 32 * H * W;
    for (int i = threadIdx.x; i < 32 * 484; i += 256) {
        int k = i / 484;
        int rem = i % 484;
        int yy = rem / 22, xx = rem % 22;
        int y = y0 - 3 + yy; y = y < 0 ? -y : (y >= H ? 2 * H - 2 - y : y);
        int x = x0 - 3 + xx; x = x < 0 ? -x : (x >= W ? 2 * W - 2 - x : x);
        p_s[i] = pb[((long)k * H + y) * W + x];
    }
    __syncthreads();
    float cen[32];
#pragma unroll
    for (int k = 0; k < 32; k++) cen[k] = p_s[k * 484 + (ty + 3) * 22 + (tx + 3)];
    float sims[49];
#pragma unroll
    for (int dy = 0; dy < 7; dy++) {
#pragma unroll
        for (int dx = 0; dx < 7; dx++) {
            float sacc = 0.f;
#pragma unroll
            for (int k = 0; k < 32; k++) sacc += p_s[k * 484 + (ty + dy) * 22 + (tx + dx)] * cen[k];
            sims[dy * 7 + dx] = sacc;
        }
    }
    float t = expf(temp[0]);
    t = fminf(fmaxf(t, 1e-4f), 1e4f);
    float m = -1e30f;
#pragma unroll
    for (int p = 0; p < 49; p++) { sims[p] *= t; m = fmaxf(m, sims[p]); }
    float ssum = 0.f;
#pragma unroll
    for (int p = 0; p < 49; p++) { sims[p] = expf(sims[p] - m); ssum += sims[p]; }
    float inv = 1.f / ssum;
    float sg = sigma[0];
    float dc = 1.f / (2.f * sg * sg);
    float csum = 0.f;
#pragma unroll
    for (int p = 0; p < 49; p++) {
        int dy = p / 7, dx = p % 7;
        float d0 = (dy - 3) / 3.f, d1 = (dx - 3) / 3.f;
        float sp = expf(-(d0 * d0 + d1 * d1) * dc);
        sims[p] = sims[p] * inv * sp;
        csum += sims[p];
    }
    float r = 1.f / fmaxf(csum, 1e-7f);
    int y = y0 + ty, x = x0 + tx;
#pragma unroll
    for (int p = 0; p < 49; p++)
        ck[(((long)b * 49 + p) * H + y) * W + x] = sims[p] * r;
}

// ---------------- bicubic 2x upsample (a=-0.75, edge clamp) ----------------
// lo: [B,256,h,w] -> hr: [B,256,2h,2w]
__global__ void k_bicubic(const float* __restrict__ lo, float* __restrict__ hr, int h, int w) {
    const int H = 2 * h, W = 2 * w;
    long idx = (long)blockIdx.x * 256 + threadIdx.x;
    long total = (long)B_ * 256 * H * W;
    if (idx >= total) return;
    int X = (int)(idx % W);
    int Y = (int)((idx / W) % H);
    long bc = idx / ((long)W * H);
    const float* lp = lo + bc * h * w;
    int iy = Y >> 1, ix = X >> 1;
    int oy = (Y & 1) ? -1 : -2;
    int ox = (X & 1) ? -1 : -2;
    float acc = 0.f;
#pragma unroll
    for (int a = 0; a < 4; a++) {
        const float WE_a = (a == 0 ? -0.03515625f : a == 1 ? 0.26171875f : a == 2 ? 0.87890625f : -0.10546875f);
        const float WO_a = (a == 0 ? -0.10546875f : a == 1 ? 0.87890625f : a == 2 ? 0.26171875f : -0.03515625f);
        float wya = (Y & 1) ? WO_a : WE_a;
        int yy = iy + oy + a; yy = yy < 0 ? 0 : (yy >= h ? h - 1 : yy);
        float rowacc = 0.f;
#pragma unroll
        for (int bb = 0; bb < 4; bb++) {
            const float WE_b = (bb == 0 ? -0.03515625f : bb == 1 ? 0.26171875f : bb == 2 ? 0.87890625f : -0.10546875f);
            const float WO_b = (bb == 0 ? -0.10546875f : bb == 1 ? 0.87890625f : bb == 2 ? 0.26171875f : -0.03515625f);
            float wxb = (X & 1) ? WO_b : WE_b;
            int xx = ix + ox + bb; xx = xx < 0 ? 0 : (xx >= w ? w - 1 : xx);
            rowacc += wxb * lp[(long)yy * w + xx];
        }
        acc += wya * rowacc;
    }
    hr[idx] = acc;
}

// ---------------- apply: out = sum_p ck[p] * hr(reflect-shift p) ----------------
// block 256; grid (W/8, H/8, B*8). Each block: 8x8 pixel tile, 32-channel chunk.
__global__ void k_apply(const float* __restrict__ ck, const float* __restrict__ hr,
                        float* __restrict__ out, int H, int W) {
    __shared__ float ck_s[49 * 64];
    __shared__ float hr_s[32 * 196];
    int x0 = blockIdx.x * 8, y0 = blockIdx.y * 8;
    int b = blockIdx.z >> 3, chunk = blockIdx.z & 7;
    int c0 = chunk * 32;
    int tid = threadIdx.x;
    const float* ckb = ck + (long)b * 49 * H * W;
    for (int i = tid; i < 49 * 64; i += 256) {
        int p = i >> 6, pix = i & 63;
        int y = y0 + (pix >> 3), x = x0 + (pix & 7);
        ck_s[i] = ckb[((long)p * H + y) * W + x];
    }
    const float* hb = hr + ((long)b * 256 + c0) * H * W;
    for (int i = tid; i < 32 * 196; i += 256) {
        int c = i / 196, rem = i % 196;
        int yy = rem / 14, xx = rem % 14;
        int y = y0 - 3 + yy; y = y < 0 ? -y : (y >= H ? 2 * H - 2 - y : y);
        int x = x0 - 3 + xx; x = x < 0 ? -x : (x >= W ? 2 * W - 2 - x : x);
        hr_s[i] = hb[((long)c * H + y) * W + x];
    }
    __syncthreads();
    int pix = tid & 63, cg = tid >> 6;
    int py = pix >> 3, px = pix & 7;
    float acc[8];
#pragma unroll
    for (int j = 0; j < 8; j++) acc[j] = 0.f;
#pragma unroll
    for (int dy = 0; dy < 7; dy++) {
#pragma unroll
        for (int dx = 0; dx < 7; dx++) {
            float cv = ck_s[(dy * 7 + dx) * 64 + pix];
            int base = (py + dy) * 14 + px + dx;
#pragma unroll
            for (int j = 0; j < 8; j++)
                acc[j] += cv * hr_s[(cg * 8 + j) * 196 + base];
        }
    }
    float* ob = out + ((long)b * 256 + c0 + cg * 8) * H * W + (long)(y0 + py) * W + (x0 + px);
#pragma unroll
    for (int j = 0; j < 8; j++)
        ob[(long)j * H * W] = acc[j];
}

// ---------------- fixup: x = x + 0.1 * fixup_w @ x, in-place per 64-pixel block ----------------
#define HW2 61440   // 192*320
__global__ void k_fixup(float* __restrict__ x, const float* __restrict__ wT) {
    __shared__ float xs[256 * 64];
    int gid = blockIdx.x;
    int b = (gid * 64) / HW2;
    int pix0 = (gid * 64) % HW2;
    int tid = threadIdx.x;
    float* xb = x + (long)b * 256 * HW2 + pix0;
    for (int i = tid; i < 256 * 64; i += 256) {
        int c = i >> 6, col = i & 63;
        xs[i] = xb[(long)c * HW2 + col];
    }
    __syncthreads();
    int p = tid & 63, og = tid >> 6;
    for (int ob = 0; ob < 16; ob++) {
        int o = og * 64 + ob * 4;
        float a0 = 0.f, a1 = 0.f, a2 = 0.f, a3 = 0.f;
        const float* wp = wT + o;
        for (int c = 0; c < 256; c++) {
            float xv = xs[c * 64 + p];
            float4 w4 = *(const float4*)(wp + (long)c * 256);
            a0 += w4.x * xv; a1 += w4.y * xv; a2 += w4.z * xv; a3 += w4.w * xv;
        }
        xb[(long)o * HW2 + p]       = xs[o * 64 + p]       + 0.1f * a0;
        xb[(long)(o + 1) * HW2 + p] = xs[(o + 1) * 64 + p] + 0.1f * a1;
        xb[(long)(o + 2) * HW2 + p] = xs[(o + 2) * 64 + p] + 0.1f * a2;
        xb[(long)(o + 3) * HW2 + p] = xs[(o + 3) * 64 + p] + 0.1f * a3;
    }
}

// ---------------- GroupNorm stats: per (b, group) mean & rstd ----------------
__global__ void k_gnstats(const float* __restrict__ x, float* __restrict__ stats) {
    __shared__ double s_s[256], q_s[256];
    int bg = blockIdx.x;  // b*32+g
    const float* xp = x + (long)bg * 8 * HW2;
    double s = 0.0, q = 0.0;
    for (int i = threadIdx.x; i < 8 * HW2; i += 256) {
        float v = xp[i];
        s += v; q += (double)v * v;
    }
    s_s[threadIdx.x] = s; q_s[threadIdx.x] = q;
    __syncthreads();
    for (int st = 128; st > 0; st >>= 1) {
        if (threadIdx.x < st) { s_s[threadIdx.x] += s_s[threadIdx.x + st]; q_s[threadIdx.x] += q_s[threadIdx.x + st]; }
        __syncthreads();
    }
    if (threadIdx.x == 0) {
        double N = 8.0 * HW2;
        double mean = s_s[0] / N;
        double var = q_s[0] / N - mean * mean;
        stats[bg * 2] = (float)mean;
        stats[bg * 2 + 1] = (float)(1.0 / sqrt(var + 1e-5));
    }
}

// ---------------- final: GN affine + conv1x1(proj_w), in-place ----------------
__global__ void k_final(float* __restrict__ x, const float* __restrict__ wT,
                        const float* __restrict__ stats,
                        const float* __restrict__ gn_w, const float* __restrict__ gn_b) {
    __shared__ float xs[256 * 64];
    int gid = blockIdx.x;
    int b = (gid * 64) / HW2;
    int pix0 = (gid * 64) % HW2;
    int tid = threadIdx.x;
    float* xb = x + (long)b * 256 * HW2 + pix0;
    for (int i = tid; i < 256 * 64; i += 256) {
        int c = i >> 6, col = i & 63;
        float mean = stats[(b * 32 + (c >> 3)) * 2];
        float rstd = stats[(b * 32 + (c >> 3)) * 2 + 1];
        float scl = rstd * gn_w[c];
        float sh = gn_b[c] - mean * scl;
        xs[i] = xb[(long)c * HW2 + col] * scl + sh;
    }
    __syncthreads();
    int p = tid & 63, og = tid >> 6;
    for (int ob = 0; ob < 16; ob++) {
        int o = og * 64 + ob * 4;
        float a0 = 0.f, a1 = 0.f, a2 = 0.f, a3 = 0.f;
        const float* wp = wT + o;
        for (int c = 0; c < 256; c++) {
            float xv = xs[c * 64 + p];
            float4 w4 = *(const float4*)(wp + (long)c * 256);
            a0 += w4.x * xv; a1 += w4.y * xv; a2 += w4.z * xv; a3 += w4.w * xv;
        }
        xb[(long)o * HW2 + p] = a0;
        xb[(long)(o + 1) * HW2 + p] = a1;
        xb[(long)(o + 2) * HW2 + p] = a2;
        xb[(long)(o + 3) * HW2 + p] = a3;
    }
}

extern "C" void kernel_launch(void* const* d_in, const int* in_sizes, int n_in,
                              void* d_out, int out_size, void* d_ws, size_t ws_size,
                              hipStream_t stream) {
    const float* src      = (const float*)d_in[0];
    const float* guidance = (const float*)d_in[1];
    const float* pre_w    = (const float*)d_in[2];
    const float* rp1_w1   = (const float*)d_in[3];
    const float* rp1_b1   = (const float*)d_in[4];
    const float* rp1_w2   = (const float*)d_in[5];
    const float* rp1_b2   = (const float*)d_in[6];
    const float* temp1    = (const float*)d_in[7];
    const float* sigma1   = (const float*)d_in[8];
    const float* rp2_w1   = (const float*)d_in[9];
    const float* rp2_b1   = (const float*)d_in[10];
    const float* rp2_w2   = (const float*)d_in[11];
    const float* rp2_b2   = (const float*)d_in[12];
    const float* temp2    = (const float*)d_in[13];
    const float* sigma2   = (const float*)d_in[14];
    const float* fixup_w  = (const float*)d_in[15];
    const float* gn_w     = (const float*)d_in[16];
    const float* gn_b     = (const float*)d_in[17];
    const float* proj_w   = (const float*)d_in[18];
    float* out = (float*)d_out;

    // ---- workspace arena ----
    char* ws = (char*)d_ws;
    size_t off = 0;
    auto alloc = [&](size_t bytes) { size_t o = off; off = (off + bytes + 255) & ~(size_t)255; return o; };
    float* gdown  = (float*)(ws + alloc((size_t)2 * 3 * 192 * 1280 * 4));   // 5.9 MB (max step)
    float* gbuf   = (float*)(ws + alloc((size_t)2 * 3 * 192 * 320 * 4));    // 1.5 MB
    float* projb  = (float*)(ws + alloc((size_t)2 * 32 * 192 * 320 * 4));   // 15.7 MB
    float* ckb    = (float*)(ws + alloc((size_t)2 * 49 * 192 * 320 * 4));   // 24.1 MB
    float* x1     = (float*)(ws + alloc((size_t)2 * 256 * 48 * 80 * 4));    // 7.9 MB
    float* out1   = (float*)(ws + alloc((size_t)2 * 256 * 96 * 160 * 4));   // 31.5 MB
    float* hrb    = (float*)(ws + alloc((size_t)2 * 256 * 192 * 320 * 4));  // 125.8 MB
    float* wTfix  = (float*)(ws + alloc(256 * 256 * 4));
    float* wTproj = (float*)(ws + alloc(256 * 256 * 4));
    float* stats  = (float*)(ws + alloc(64 * 2 * 4));

    // weight transposes
    k_transpose<<<(65536 + 255) / 256, 256, 0, stream>>>(fixup_w, wTfix, 256, 256);
    k_transpose<<<(65536 + 255) / 256, 256, 0, stream>>>(proj_w, wTproj, 256, 256);

    // pre-projection 384->256
    k_preproj<<<512, 256, 0, stream>>>(src, pre_w, x1);

    // ---- JBU step 1: 48x80 -> 96x160 ----
    {
        const int H = 96, W = 160, HW = H * W;
        k_down_h<<<(2 * 3 * H * 1280) / 256, 256, 0, stream>>>(guidance, gdown, H, 8.f);
        k_down_w<<<(2 * 3 * HW + 255) / 256, 256, 0, stream>>>(gdown, gbuf, H, W, 8.f);
        k_proj<<<(2 * HW + 255) / 256, 256, 0, stream>>>(gbuf, projb, rp1_w1, rp1_b1, rp1_w2, rp1_b2, HW);
        k_ck<<<dim3(W / 16, H / 16, 2), 256, 0, stream>>>(projb, ckb, temp1, sigma1, H, W);
        k_bicubic<<<(2 * 256 * HW) / 256, 256, 0, stream>>>(x1, hrb, 48, 80);
        k_apply<<<dim3(W / 8, H / 8, 16), 256, 0, stream>>>(ckb, hrb, out1, H, W);
    }

    // ---- JBU step 2: 96x160 -> 192x320 ----
    {
        const int H = 192, W = 320, HW = H * W;
        k_down_h<<<(2 * 3 * H * 1280) / 256, 256, 0, stream>>>(guidance, gdown, H, 4.f);
        k_down_w<<<(2 * 3 * HW + 255) / 256, 256, 0, stream>>>(gdown, gbuf, H, W, 4.f);
        k_proj<<<(2 * HW + 255) / 256, 256, 0, stream>>>(gbuf, projb, rp2_w1, rp2_b1, rp2_w2, rp2_b2, HW);
        k_ck<<<dim3(W / 16, H / 16, 2), 256, 0, stream>>>(projb, ckb, temp2, sigma2, H, W);
        k_bicubic<<<(2 * 256 * HW) / 256, 256, 0, stream>>>(out1, hrb, 96, 160);
        k_apply<<<dim3(W / 8, H / 8, 16), 256, 0, stream>>>(ckb, hrb, out, H, W);
    }

    // ---- fixup residual (in-place on d_out) ----
    k_fixup<<<(2 * HW2) / 64, 256, 0, stream>>>(out, wTfix);
    // ---- GroupNorm stats ----
    k_gnstats<<<64, 256, 0, stream>>>(out, stats);
    // ---- GN affine + final projection (in-place on d_out) ----
    k_final<<<(2 * HW2) / 64, 256, 0, stream>>>(out, wTproj, stats, gn_w, gn_b);
}

// Round 2
// 1191.807 us; speedup vs baseline: 2.8444x; 2.8444x over previous
//
#include <hip/hip_runtime.h>
#include <math.h>

#define B_ 2
#define C_ 256
#define FD_ 384
#define K_ 32
#define HW2 61440   // 192*320

typedef __attribute__((ext_vector_type(8))) short s8b;      // 8 bf16 (4 VGPRs)
typedef __attribute__((ext_vector_type(16))) float fvec16;  // MFMA 32x32 accumulator

__device__ __forceinline__ unsigned short f2bf(float f) {
    unsigned int u = __builtin_bit_cast(unsigned int, f);
    u = (u + 0x7fffu + ((u >> 16) & 1u)) >> 16;
    return (unsigned short)u;
}

// ---------------- pre_proj: conv1x1 384->256 over 48x80 ----------------
__global__ void k_preproj(const float* __restrict__ src, const float* __restrict__ w,
                          float* __restrict__ out) {
    __shared__ float w_s[FD_];
    int bo = blockIdx.x;
    int b = bo >> 8, o = bo & 255;
    int tid = threadIdx.x;
    for (int i = tid; i < FD_; i += 256) w_s[i] = w[o * FD_ + i];
    __syncthreads();
    float acc[15];
#pragma unroll
    for (int k = 0; k < 15; k++) acc[k] = 0.f;
    const float* sp = src + (long)b * FD_ * 3840;
    for (int c = 0; c < FD_; c++) {
        float wv = w_s[c];
        const float* row = sp + (long)c * 3840;
#pragma unroll
        for (int k = 0; k < 15; k++) acc[k] += wv * row[tid + k * 256];
    }
    float* op = out + ((long)b * 256 + o) * 3840;
#pragma unroll
    for (int k = 0; k < 15; k++) op[tid + k * 256] = acc[k];
}

// ---------------- guidance downsample (tent, antialias) ----------------
__global__ void k_down_h(const float* __restrict__ in, float* __restrict__ out, int Ho, float s) {
    long idx = (long)blockIdx.x * 256 + threadIdx.x;
    long total = (long)B_ * 3 * Ho * 1280;
    if (idx >= total) return;
    int x = (int)(idx % 1280);
    long t1 = idx / 1280;
    int i = (int)(t1 % Ho);
    long t2 = t1 / Ho;
    int c = (int)(t2 % 3);
    int b = (int)(t2 / 3);
    float sf = (i + 0.5f) * s - 0.5f;
    int j0 = (int)floorf(sf - s) + 1;
    int j1 = (int)ceilf(sf + s) - 1;
    float acc = 0.f, wsum = 0.f;
    const float* ip = in + ((long)(b * 3 + c) * 768) * 1280 + x;
    for (int j = j0; j <= j1; j++) {
        if (j < 0 || j >= 768) continue;
        float wv = 1.f - fabsf((float)j - sf) / s;
        acc += wv * ip[(long)j * 1280];
        wsum += wv;
    }
    out[idx] = acc / wsum;
}

__global__ void k_down_w(const float* __restrict__ in, float* __restrict__ out, int Ho, int Wo, float s) {
    long idx = (long)blockIdx.x * 256 + threadIdx.x;
    long total = (long)B_ * 3 * Ho * Wo;
    if (idx >= total) return;
    int i = (int)(idx % Wo);
    long t1 = idx / Wo;
    int y = (int)(t1 % Ho);
    long t2 = t1 / Ho;
    int c = (int)(t2 % 3);
    int b = (int)(t2 / 3);
    float sf = (i + 0.5f) * s - 0.5f;
    int j0 = (int)floorf(sf - s) + 1;
    int j1 = (int)ceilf(sf + s) - 1;
    float acc = 0.f, wsum = 0.f;
    const float* ip = in + ((long)(b * 3 + c) * Ho + y) * 1280;
    for (int j = j0; j <= j1; j++) {
        if (j < 0 || j >= 1280) continue;
        float wv = 1.f - fabsf((float)j - sf) / s;
        acc += wv * ip[j];
        wsum += wv;
    }
    out[idx] = acc / wsum;
}

// ---------------- range projection MLP ----------------
__global__ void k_proj(const float* __restrict__ g, float* __restrict__ proj,
                       const float* __restrict__ w1, const float* __restrict__ b1,
                       const float* __restrict__ w2, const float* __restrict__ b2,
                       int HW) {
    __shared__ float w1_s[96], b1_s[32], w2_s[1024], b2_s[32];
    int tid = threadIdx.x;
    if (tid < 96) w1_s[tid] = w1[tid];
    if (tid < 32) { b1_s[tid] = b1[tid]; b2_s[tid] = b2[tid]; }
    for (int i = tid; i < 1024; i += 256) w2_s[i] = w2[i];
    __syncthreads();
    long idx = (long)blockIdx.x * 256 + tid;
    if (idx >= (long)B_ * HW) return;
    int b = (int)(idx / HW);
    int pix = (int)(idx % HW);
    const float* gp = g + (long)b * 3 * HW + pix;
    float g0 = gp[0], g1 = gp[HW], g2 = gp[2 * (long)HW];
    float hg[32];
#pragma unroll
    for (int k = 0; k < 32; k++) {
        float h = b1_s[k] + w1_s[k * 3] * g0 + w1_s[k * 3 + 1] * g1 + w1_s[k * 3 + 2] * g2;
        hg[k] = 0.5f * h * (1.f + erff(h * 0.70710678118654752f));
    }
    float* pp = proj + (long)b * 32 * HW + pix;
#pragma unroll
    for (int j = 0; j < 32; j++) {
        float a = b2_s[j];
#pragma unroll
        for (int k = 0; k < 32; k++) a += w2_s[j * 32 + k] * hg[k];
        pp[(long)j * HW] = a;
    }
}

// ---------------- sims + softmax + spatial + renorm -> ck ----------------
__global__ void k_ck(const float* __restrict__ proj, float* __restrict__ ck,
                     const float* __restrict__ temp, const float* __restrict__ sigma,
                     int H, int W) {
    __shared__ float p_s[32 * 22 * 22];
    int tx = threadIdx.x & 15, ty = threadIdx.x >> 4;
    int x0 = blockIdx.x * 16, y0 = blockIdx.y * 16;
    int b = blockIdx.z;
    const float* pb = proj + (long)b * 32 * H * W;
    for (int i = threadIdx.x; i < 32 * 484; i += 256) {
        int k = i / 484;
        int rem = i % 484;
        int yy = rem / 22, xx = rem % 22;
        int y = y0 - 3 + yy; y = y < 0 ? -y : (y >= H ? 2 * H - 2 - y : y);
        int x = x0 - 3 + xx; x = x < 0 ? -x : (x >= W ? 2 * W - 2 - x : x);
        p_s[i] = pb[((long)k * H + y) * W + x];
    }
    __syncthreads();
    float cen[32];
#pragma unroll
    for (int k = 0; k < 32; k++) cen[k] = p_s[k * 484 + (ty + 3) * 22 + (tx + 3)];
    float sims[49];
#pragma unroll
    for (int dy = 0; dy < 7; dy++) {
#pragma unroll
        for (int dx = 0; dx < 7; dx++) {
            float sacc = 0.f;
#pragma unroll
            for (int k = 0; k < 32; k++) sacc += p_s[k * 484 + (ty + dy) * 22 + (tx + dx)] * cen[k];
            sims[dy * 7 + dx] = sacc;
        }
    }
    float t = expf(temp[0]);
    t = fminf(fmaxf(t, 1e-4f), 1e4f);
    float m = -1e30f;
#pragma unroll
    for (int p = 0; p < 49; p++) { sims[p] *= t; m = fmaxf(m, sims[p]); }
    float ssum = 0.f;
#pragma unroll
    for (int p = 0; p < 49; p++) { sims[p] = expf(sims[p] - m); ssum += sims[p]; }
    float inv = 1.f / ssum;
    float sg = sigma[0];
    float dc = 1.f / (2.f * sg * sg);
    float csum = 0.f;
#pragma unroll
    for (int p = 0; p < 49; p++) {
        int dy = p / 7, dx = p % 7;
        float d0 = (dy - 3) / 3.f, d1 = (dx - 3) / 3.f;
        float sp = expf(-(d0 * d0 + d1 * d1) * dc);
        sims[p] = sims[p] * inv * sp;
        csum += sims[p];
    }
    float r = 1.f / fmaxf(csum, 1e-7f);
    int y = y0 + ty, x = x0 + tx;
#pragma unroll
    for (int p = 0; p < 49; p++)
        ck[(((long)b * 49 + p) * H + y) * W + x] = sims[p] * r;
}

// ---------------- bicubic 2x upsample ----------------
__global__ void k_bicubic(const float* __restrict__ lo, float* __restrict__ hr, int h, int w) {
    const int H = 2 * h, W = 2 * w;
    long idx = (long)blockIdx.x * 256 + threadIdx.x;
    long total = (long)B_ * 256 * H * W;
    if (idx >= total) return;
    int X = (int)(idx % W);
    int Y = (int)((idx / W) % H);
    long bc = idx / ((long)W * H);
    const float* lp = lo + bc * h * w;
    int iy = Y >> 1, ix = X >> 1;
    int oy = (Y & 1) ? -1 : -2;
    int ox = (X & 1) ? -1 : -2;
    float acc = 0.f;
#pragma unroll
    for (int a = 0; a < 4; a++) {
        const float WE_a = (a == 0 ? -0.03515625f : a == 1 ? 0.26171875f : a == 2 ? 0.87890625f : -0.10546875f);
        const float WO_a = (a == 0 ? -0.10546875f : a == 1 ? 0.87890625f : a == 2 ? 0.26171875f : -0.03515625f);
        float wya = (Y & 1) ? WO_a : WE_a;
        int yy = iy + oy + a; yy = yy < 0 ? 0 : (yy >= h ? h - 1 : yy);
        float rowacc = 0.f;
#pragma unroll
        for (int bb = 0; bb < 4; bb++) {
            const float WE_b = (bb == 0 ? -0.03515625f : bb == 1 ? 0.26171875f : bb == 2 ? 0.87890625f : -0.10546875f);
            const float WO_b = (bb == 0 ? -0.10546875f : bb == 1 ? 0.87890625f : bb == 2 ? 0.26171875f : -0.03515625f);
            float wxb = (X & 1) ? WO_b : WE_b;
            int xx = ix + ox + bb; xx = xx < 0 ? 0 : (xx >= w ? w - 1 : xx);
            rowacc += wxb * lp[(long)yy * w + xx];
        }
        acc += wya * rowacc;
    }
    hr[idx] = acc;
}

// ---------------- apply ----------------
__global__ void k_apply(const float* __restrict__ ck, const float* __restrict__ hr,
                        float* __restrict__ out, int H, int W) {
    __shared__ float ck_s[49 * 64];
    __shared__ float hr_s[32 * 196];
    int x0 = blockIdx.x * 8, y0 = blockIdx.y * 8;
    int b = blockIdx.z >> 3, chunk = blockIdx.z & 7;
    int c0 = chunk * 32;
    int tid = threadIdx.x;
    const float* ckb = ck + (long)b * 49 * H * W;
    for (int i = tid; i < 49 * 64; i += 256) {
        int p = i >> 6, pix = i & 63;
        int y = y0 + (pix >> 3), x = x0 + (pix & 7);
        ck_s[i] = ckb[((long)p * H + y) * W + x];
    }
    const float* hb = hr + ((long)b * 256 + c0) * H * W;
    for (int i = tid; i < 32 * 196; i += 256) {
        int c = i / 196, rem = i % 196;
        int yy = rem / 14, xx = rem % 14;
        int y = y0 - 3 + yy; y = y < 0 ? -y : (y >= H ? 2 * H - 2 - y : y);
        int x = x0 - 3 + xx; x = x < 0 ? -x : (x >= W ? 2 * W - 2 - x : x);
        hr_s[i] = hb[((long)c * H + y) * W + x];
    }
    __syncthreads();
    int pix = tid & 63, cg = tid >> 6;
    int py = pix >> 3, px = pix & 7;
    float acc[8];
#pragma unroll
    for (int j = 0; j < 8; j++) acc[j] = 0.f;
#pragma unroll
    for (int dy = 0; dy < 7; dy++) {
#pragma unroll
        for (int dx = 0; dx < 7; dx++) {
            float cv = ck_s[(dy * 7 + dx) * 64 + pix];
            int base = (py + dy) * 14 + px + dx;
#pragma unroll
            for (int j = 0; j < 8; j++)
                acc[j] += cv * hr_s[(cg * 8 + j) * 196 + base];
        }
    }
    float* ob = out + ((long)b * 256 + c0 + cg * 8) * H * W + (long)(y0 + py) * W + (x0 + px);
#pragma unroll
    for (int j = 0; j < 8; j++)
        ob[(long)j * H * W] = acc[j];
}

// ---------------- prep: pack W[o][c] fp32 -> bf16 MFMA A-fragment order ----------------
// layout: wf[((mt*16+ks)*64 + lane)*8 + j] = bf16(w[mt*32+(lane&31)][ks*16+(lane>>5)*8+j])
__global__ void k_prepw(const float* __restrict__ w, unsigned short* __restrict__ wf) {
    int blk = blockIdx.x;           // mt*16+ks, 128 blocks
    int lane = threadIdx.x;         // 64
    int mt = blk >> 4, ks = blk & 15;
    int o = mt * 32 + (lane & 31);
    int c = ks * 16 + (lane >> 5) * 8;
    const float* wp = w + (long)o * 256 + c;
    float4 v0 = *(const float4*)wp;
    float4 v1 = *(const float4*)(wp + 4);
    unsigned short* dst = wf + ((long)(blk * 64 + lane)) * 8;
    unsigned int r0 = f2bf(v0.x) | ((unsigned int)f2bf(v0.y) << 16);
    unsigned int r1 = f2bf(v0.z) | ((unsigned int)f2bf(v0.w) << 16);
    unsigned int r2 = f2bf(v1.x) | ((unsigned int)f2bf(v1.y) << 16);
    unsigned int r3 = f2bf(v1.z) | ((unsigned int)f2bf(v1.w) << 16);
    uint4 pk = {r0, r1, r2, r3};
    *(uint4*)dst = pk;
}

// ---------------- MFMA GEMM: y = W @ x (+ optional GN-fold on x, + optional residual) ----
// x: [B,256,HW2] fp32; wf: bf16 frag-ordered; in-place on x.
// grid (960, B), block 256 (4 waves). Tile: 256 outputs x 64 pixels.
#define LDK 264   // LDS row stride in halfs (pad for bank conflicts)
template <bool GN, bool RESID>
__global__ __launch_bounds__(256) void k_gemm256(float* __restrict__ x,
                                                 const unsigned short* __restrict__ wf,
                                                 const float* __restrict__ stats,
                                                 const float* __restrict__ gn_w,
                                                 const float* __restrict__ gn_b) {
    __shared__ unsigned short xs[64 * LDK];
    __shared__ float scl_s[256], sh_s[256];
    int tid = threadIdx.x;
    int b = blockIdx.y;
    int pix0 = blockIdx.x * 64;
    float* xb = x + (long)b * 256 * HW2;

    if (GN) {
        int c = tid;
        int g = c >> 3;
        float mean = stats[(b * 32 + g) * 2];
        float rstd = stats[(b * 32 + g) * 2 + 1];
        float s = rstd * gn_w[c];
        scl_s[c] = s;
        sh_s[c] = gn_b[c] - mean * s;
        __syncthreads();
    }

    // stage X tile [256 c x 64 pix] -> LDS bf16 transposed [pix][c]
#pragma unroll
    for (int it = 0; it < 4; it++) {
        int c0 = ((tid >> 4) << 2) + it * 64;
        int px = (tid & 15) << 2;
        const float* gp = xb + (long)c0 * HW2 + pix0 + px;
        float4 v0 = *(const float4*)gp;
        float4 v1 = *(const float4*)(gp + HW2);
        float4 v2 = *(const float4*)(gp + 2 * HW2);
        float4 v3 = *(const float4*)(gp + 3 * HW2);
        if (GN) {
            float s0 = scl_s[c0], h0 = sh_s[c0];
            float s1 = scl_s[c0 + 1], h1 = sh_s[c0 + 1];
            float s2 = scl_s[c0 + 2], h2 = sh_s[c0 + 2];
            float s3 = scl_s[c0 + 3], h3 = sh_s[c0 + 3];
            v0.x = v0.x * s0 + h0; v0.y = v0.y * s0 + h0; v0.z = v0.z * s0 + h0; v0.w = v0.w * s0 + h0;
            v1.x = v1.x * s1 + h1; v1.y = v1.y * s1 + h1; v1.z = v1.z * s1 + h1; v1.w = v1.w * s1 + h1;
            v2.x = v2.x * s2 + h2; v2.y = v2.y * s2 + h2; v2.z = v2.z * s2 + h2; v2.w = v2.w * s2 + h2;
            v3.x = v3.x * s3 + h3; v3.y = v3.y * s3 + h3; v3.z = v3.z * s3 + h3; v3.w = v3.w * s3 + h3;
        }
        float p0[4] = {v0.x, v0.y, v0.z, v0.w};
        float p1[4] = {v1.x, v1.y, v1.z, v1.w};
        float p2[4] = {v2.x, v2.y, v2.z, v2.w};
        float p3[4] = {v3.x, v3.y, v3.z, v3.w};
#pragma unroll
        for (int p = 0; p < 4; p++) {
            ushort4 u;
            u.x = f2bf(p0[p]); u.y = f2bf(p1[p]); u.z = f2bf(p2[p]); u.w = f2bf(p3[p]);
            *(ushort4*)&xs[(px + p) * LDK + c0] = u;
        }
    }
    __syncthreads();

    int lane = tid & 63, wv = tid >> 6;
    fvec16 acc[2][2];
#pragma unroll
    for (int mi = 0; mi < 2; mi++)
#pragma unroll
        for (int ni = 0; ni < 2; ni++)
            acc[mi][ni] = (fvec16)(0.f);

    int n_in = lane & 31;
    int koff = (lane >> 5) * 8;
#pragma unroll
    for (int ks = 0; ks < 16; ks++) {
        s8b a0 = *(const s8b*)(wf + ((long)(((wv * 2 + 0) * 16 + ks) * 64 + lane)) * 8);
        s8b a1 = *(const s8b*)(wf + ((long)(((wv * 2 + 1) * 16 + ks) * 64 + lane)) * 8);
        s8b b0 = *(const s8b*)&xs[(0 + n_in) * LDK + ks * 16 + koff];
        s8b b1 = *(const s8b*)&xs[(32 + n_in) * LDK + ks * 16 + koff];
        acc[0][0] = __builtin_amdgcn_mfma_f32_32x32x16_bf16(a0, b0, acc[0][0], 0, 0, 0);
        acc[0][1] = __builtin_amdgcn_mfma_f32_32x32x16_bf16(a0, b1, acc[0][1], 0, 0, 0);
        acc[1][0] = __builtin_amdgcn_mfma_f32_32x32x16_bf16(a1, b0, acc[1][0], 0, 0, 0);
        acc[1][1] = __builtin_amdgcn_mfma_f32_32x32x16_bf16(a1, b1, acc[1][1], 0, 0, 0);
    }

    int h = lane >> 5;
#pragma unroll
    for (int mi = 0; mi < 2; mi++) {
        int mt = wv * 2 + mi;
#pragma unroll
        for (int ni = 0; ni < 2; ni++) {
            int pix = pix0 + ni * 32 + n_in;
#pragma unroll
            for (int r = 0; r < 16; r++) {
                int row = (r & 3) + 8 * (r >> 2) + 4 * h;
                long addr = (long)(mt * 32 + row) * HW2 + pix;
                if (RESID)
                    xb[addr] = xb[addr] + 0.1f * acc[mi][ni][r];
                else
                    xb[addr] = acc[mi][ni][r];
            }
        }
    }
}

// ---------------- GroupNorm stats: 2-pass ----------------
// pass 1: 1024 blocks (bg = blk>>4, chunk = blk&15), partial double sums
__global__ void k_gnpart(const float* __restrict__ x, double* __restrict__ part) {
    __shared__ double s_s[256], q_s[256];
    int blk = blockIdx.x;
    int bg = blk >> 4, ch = blk & 15;
    const int CHUNK = 8 * HW2 / 16;  // 30720
    const float* xp = x + (long)bg * 8 * HW2 + (long)ch * CHUNK;
    double s = 0.0, q = 0.0;
    for (int i = threadIdx.x; i < CHUNK; i += 256) {
        float v = xp[i];
        s += v; q += (double)v * v;
    }
    s_s[threadIdx.x] = s; q_s[threadIdx.x] = q;
    __syncthreads();
    for (int st = 128; st > 0; st >>= 1) {
        if (threadIdx.x < st) { s_s[threadIdx.x] += s_s[threadIdx.x + st]; q_s[threadIdx.x] += q_s[threadIdx.x + st]; }
        __syncthreads();
    }
    if (threadIdx.x == 0) {
        part[blk * 2] = s_s[0];
        part[blk * 2 + 1] = q_s[0];
    }
}

__global__ void k_gnred(const double* __restrict__ part, float* __restrict__ stats) {
    int bg = threadIdx.x;  // 64
    double s = 0.0, q = 0.0;
    for (int ch = 0; ch < 16; ch++) {
        s += part[(bg * 16 + ch) * 2];
        q += part[(bg * 16 + ch) * 2 + 1];
    }
    double N = 8.0 * HW2;
    double mean = s / N;
    double var = q / N - mean * mean;
    stats[bg * 2] = (float)mean;
    stats[bg * 2 + 1] = (float)(1.0 / sqrt(var + 1e-5));
}

extern "C" void kernel_launch(void* const* d_in, const int* in_sizes, int n_in,
                              void* d_out, int out_size, void* d_ws, size_t ws_size,
                              hipStream_t stream) {
    const float* src      = (const float*)d_in[0];
    const float* guidance = (const float*)d_in[1];
    const float* pre_w    = (const float*)d_in[2];
    const float* rp1_w1   = (const float*)d_in[3];
    const float* rp1_b1   = (const float*)d_in[4];
    const float* rp1_w2   = (const float*)d_in[5];
    const float* rp1_b2   = (const float*)d_in[6];
    const float* temp1    = (const float*)d_in[7];
    const float* sigma1   = (const float*)d_in[8];
    const float* rp2_w1   = (const float*)d_in[9];
    const float* rp2_b1   = (const float*)d_in[10];
    const float* rp2_w2   = (const float*)d_in[11];
    const float* rp2_b2   = (const float*)d_in[12];
    const float* temp2    = (const float*)d_in[13];
    const float* sigma2   = (const float*)d_in[14];
    const float* fixup_w  = (const float*)d_in[15];
    const float* gn_w     = (const float*)d_in[16];
    const float* gn_b     = (const float*)d_in[17];
    const float* proj_w   = (const float*)d_in[18];
    float* out = (float*)d_out;

    // ---- workspace arena ----
    char* ws = (char*)d_ws;
    size_t off = 0;
    auto alloc = [&](size_t bytes) { size_t o = off; off = (off + bytes + 255) & ~(size_t)255; return o; };
    float* gdown  = (float*)(ws + alloc((size_t)2 * 3 * 192 * 1280 * 4));
    float* gbuf   = (float*)(ws + alloc((size_t)2 * 3 * 192 * 320 * 4));
    float* projb  = (float*)(ws + alloc((size_t)2 * 32 * 192 * 320 * 4));
    float* ckb    = (float*)(ws + alloc((size_t)2 * 49 * 192 * 320 * 4));
    float* x1     = (float*)(ws + alloc((size_t)2 * 256 * 48 * 80 * 4));
    float* out1   = (float*)(ws + alloc((size_t)2 * 256 * 96 * 160 * 4));
    float* hrb    = (float*)(ws + alloc((size_t)2 * 256 * 192 * 320 * 4));
    unsigned short* wfFix  = (unsigned short*)(ws + alloc(65536 * 2));
    unsigned short* wfProj = (unsigned short*)(ws + alloc(65536 * 2));
    double* gpart = (double*)(ws + alloc(1024 * 2 * 8));
    float* stats  = (float*)(ws + alloc(64 * 2 * 4));

    // weight prep (bf16 MFMA fragment order)
    k_prepw<<<128, 64, 0, stream>>>(fixup_w, wfFix);
    k_prepw<<<128, 64, 0, stream>>>(proj_w, wfProj);

    // pre-projection 384->256
    k_preproj<<<512, 256, 0, stream>>>(src, pre_w, x1);

    // ---- JBU step 1: 48x80 -> 96x160 ----
    {
        const int H = 96, W = 160, HW = H * W;
        k_down_h<<<(2 * 3 * H * 1280) / 256, 256, 0, stream>>>(guidance, gdown, H, 8.f);
        k_down_w<<<(2 * 3 * HW + 255) / 256, 256, 0, stream>>>(gdown, gbuf, H, W, 8.f);
        k_proj<<<(2 * HW + 255) / 256, 256, 0, stream>>>(gbuf, projb, rp1_w1, rp1_b1, rp1_w2, rp1_b2, HW);
        k_ck<<<dim3(W / 16, H / 16, 2), 256, 0, stream>>>(projb, ckb, temp1, sigma1, H, W);
        k_bicubic<<<(2 * 256 * HW) / 256, 256, 0, stream>>>(x1, hrb, 48, 80);
        k_apply<<<dim3(W / 8, H / 8, 16), 256, 0, stream>>>(ckb, hrb, out1, H, W);
    }

    // ---- JBU step 2: 96x160 -> 192x320 ----
    {
        const int H = 192, W = 320, HW = H * W;
        k_down_h<<<(2 * 3 * H * 1280) / 256, 256, 0, stream>>>(guidance, gdown, H, 4.f);
        k_down_w<<<(2 * 3 * HW + 255) / 256, 256, 0, stream>>>(gdown, gbuf, H, W, 4.f);
        k_proj<<<(2 * HW + 255) / 256, 256, 0, stream>>>(gbuf, projb, rp2_w1, rp2_b1, rp2_w2, rp2_b2, HW);
        k_ck<<<dim3(W / 16, H / 16, 2), 256, 0, stream>>>(projb, ckb, temp2, sigma2, H, W);
        k_bicubic<<<(2 * 256 * HW) / 256, 256, 0, stream>>>(out1, hrb, 96, 160);
        k_apply<<<dim3(W / 8, H / 8, 16), 256, 0, stream>>>(ckb, hrb, out, H, W);
    }

    // ---- fixup residual: out = out + 0.1 * W @ out (MFMA, in-place) ----
    k_gemm256<false, true><<<dim3(960, 2), 256, 0, stream>>>(out, wfFix, nullptr, nullptr, nullptr);
    // ---- GroupNorm stats (2-pass) ----
    k_gnpart<<<1024, 256, 0, stream>>>(out, gpart);
    k_gnred<<<1, 64, 0, stream>>>(gpart, stats);
    // ---- GN affine + final projection (MFMA, in-place) ----
    k_gemm256<true, false><<<dim3(960, 2), 256, 0, stream>>>(out, wfProj, stats, gn_w, gn_b);
}

// Round 3
// 1045.090 us; speedup vs baseline: 3.2437x; 1.1404x over previous
//
#include <hip/hip_runtime.h>
#include <math.h>

#define B_ 2
#define C_ 256
#define FD_ 384
#define K_ 32
#define HW2 61440   // 192*320

typedef __attribute__((ext_vector_type(8))) short s8b;      // 8 bf16 (4 VGPRs)
typedef __attribute__((ext_vector_type(16))) float fvec16;  // MFMA 32x32 accumulator

__device__ __forceinline__ unsigned short f2bf(float f) {
    unsigned int u = __builtin_bit_cast(unsigned int, f);
    u = (u + 0x7fffu + ((u >> 16) & 1u)) >> 16;
    return (unsigned short)u;
}

// ---------------- pre_proj: conv1x1 384->256 over 48x80 ----------------
__global__ void k_preproj(const float* __restrict__ src, const float* __restrict__ w,
                          float* __restrict__ out) {
    __shared__ float w_s[FD_];
    int bo = blockIdx.x;
    int b = bo >> 8, o = bo & 255;
    int tid = threadIdx.x;
    for (int i = tid; i < FD_; i += 256) w_s[i] = w[o * FD_ + i];
    __syncthreads();
    float acc[15];
#pragma unroll
    for (int k = 0; k < 15; k++) acc[k] = 0.f;
    const float* sp = src + (long)b * FD_ * 3840;
    for (int c = 0; c < FD_; c++) {
        float wv = w_s[c];
        const float* row = sp + (long)c * 3840;
#pragma unroll
        for (int k = 0; k < 15; k++) acc[k] += wv * row[tid + k * 256];
    }
    float* op = out + ((long)b * 256 + o) * 3840;
#pragma unroll
    for (int k = 0; k < 15; k++) op[tid + k * 256] = acc[k];
}

// ---------------- guidance downsample (tent, antialias) ----------------
__global__ void k_down_h(const float* __restrict__ in, float* __restrict__ out, int Ho, float s) {
    long idx = (long)blockIdx.x * 256 + threadIdx.x;
    long total = (long)B_ * 3 * Ho * 1280;
    if (idx >= total) return;
    int x = (int)(idx % 1280);
    long t1 = idx / 1280;
    int i = (int)(t1 % Ho);
    long t2 = t1 / Ho;
    int c = (int)(t2 % 3);
    int b = (int)(t2 / 3);
    float sf = (i + 0.5f) * s - 0.5f;
    int j0 = (int)floorf(sf - s) + 1;
    int j1 = (int)ceilf(sf + s) - 1;
    float acc = 0.f, wsum = 0.f;
    const float* ip = in + ((long)(b * 3 + c) * 768) * 1280 + x;
    for (int j = j0; j <= j1; j++) {
        if (j < 0 || j >= 768) continue;
        float wv = 1.f - fabsf((float)j - sf) / s;
        acc += wv * ip[(long)j * 1280];
        wsum += wv;
    }
    out[idx] = acc / wsum;
}

__global__ void k_down_w(const float* __restrict__ in, float* __restrict__ out, int Ho, int Wo, float s) {
    long idx = (long)blockIdx.x * 256 + threadIdx.x;
    long total = (long)B_ * 3 * Ho * Wo;
    if (idx >= total) return;
    int i = (int)(idx % Wo);
    long t1 = idx / Wo;
    int y = (int)(t1 % Ho);
    long t2 = t1 / Ho;
    int c = (int)(t2 % 3);
    int b = (int)(t2 / 3);
    float sf = (i + 0.5f) * s - 0.5f;
    int j0 = (int)floorf(sf - s) + 1;
    int j1 = (int)ceilf(sf + s) - 1;
    float acc = 0.f, wsum = 0.f;
    const float* ip = in + ((long)(b * 3 + c) * Ho + y) * 1280;
    for (int j = j0; j <= j1; j++) {
        if (j < 0 || j >= 1280) continue;
        float wv = 1.f - fabsf((float)j - sf) / s;
        acc += wv * ip[j];
        wsum += wv;
    }
    out[idx] = acc / wsum;
}

// ---------------- range projection MLP ----------------
__global__ void k_proj(const float* __restrict__ g, float* __restrict__ proj,
                       const float* __restrict__ w1, const float* __restrict__ b1,
                       const float* __restrict__ w2, const float* __restrict__ b2,
                       int HW) {
    __shared__ float w1_s[96], b1_s[32], w2_s[1024], b2_s[32];
    int tid = threadIdx.x;
    if (tid < 96) w1_s[tid] = w1[tid];
    if (tid < 32) { b1_s[tid] = b1[tid]; b2_s[tid] = b2[tid]; }
    for (int i = tid; i < 1024; i += 256) w2_s[i] = w2[i];
    __syncthreads();
    long idx = (long)blockIdx.x * 256 + tid;
    if (idx >= (long)B_ * HW) return;
    int b = (int)(idx / HW);
    int pix = (int)(idx % HW);
    const float* gp = g + (long)b * 3 * HW + pix;
    float g0 = gp[0], g1 = gp[HW], g2 = gp[2 * (long)HW];
    float hg[32];
#pragma unroll
    for (int k = 0; k < 32; k++) {
        float h = b1_s[k] + w1_s[k * 3] * g0 + w1_s[k * 3 + 1] * g1 + w1_s[k * 3 + 2] * g2;
        hg[k] = 0.5f * h * (1.f + erff(h * 0.70710678118654752f));
    }
    float* pp = proj + (long)b * 32 * HW + pix;
#pragma unroll
    for (int j = 0; j < 32; j++) {
        float a = b2_s[j];
#pragma unroll
        for (int k = 0; k < 32; k++) a += w2_s[j * 32 + k] * hg[k];
        pp[(long)j * HW] = a;
    }
}

// ======== FUSED: sims+softmax+spatial+renorm (ck in regs) + bicubic-in-LDS + apply ========
// grid (W/16, H/16, B*CS); 256 threads; 16x16 px tile; channels split CS ways.
// lo: [B,256,h,w], proj: [B,32,H,W], out: [B,256,H,W] with H=2h, W=2w.
template <int CS>
__global__ __launch_bounds__(256) void k_fused(const float* __restrict__ lo,
                                               const float* __restrict__ proj,
                                               float* __restrict__ out,
                                               const float* __restrict__ temp,
                                               const float* __restrict__ sigma,
                                               int H, int W, int h, int w) {
    __shared__ float smem[15488];            // phase1: proj halo [32][22*22]
    float* lo_s  = smem;                     // phase2: [8][16][16]
    float* tmp_s = smem + 2048;              // phase2: [8][16][23]
    float* hr_s  = smem + 2048 + 2944;       // phase2: [8][22][23]

    int tid = threadIdx.x;
    int tx = tid & 15, ty = tid >> 4;
    int x0 = blockIdx.x * 16, y0 = blockIdx.y * 16;
    int b = blockIdx.z / CS;
    int c_base = (blockIdx.z % CS) * (256 / CS);

    // ---- phase 1: stage proj halo, compute ck[49] in registers ----
    const float* pb = proj + (long)b * 32 * H * W;
    for (int i = tid; i < 32 * 484; i += 256) {
        int k = i / 484;
        int rem = i % 484;
        int yy = rem / 22, xx = rem % 22;
        int y = y0 - 3 + yy; y = y < 0 ? -y : (y >= H ? 2 * H - 2 - y : y);
        int x = x0 - 3 + xx; x = x < 0 ? -x : (x >= W ? 2 * W - 2 - x : x);
        smem[i] = pb[((long)k * H + y) * W + x];
    }
    __syncthreads();
    float ck[49];
    {
        float cen[32];
#pragma unroll
        for (int k = 0; k < 32; k++) cen[k] = smem[k * 484 + (ty + 3) * 22 + (tx + 3)];
#pragma unroll
        for (int dy = 0; dy < 7; dy++) {
#pragma unroll
            for (int dx = 0; dx < 7; dx++) {
                float sacc = 0.f;
#pragma unroll
                for (int k = 0; k < 32; k++) sacc += smem[k * 484 + (ty + dy) * 22 + (tx + dx)] * cen[k];
                ck[dy * 7 + dx] = sacc;
            }
        }
    }
    {
        float t = expf(temp[0]);
        t = fminf(fmaxf(t, 1e-4f), 1e4f);
        float m = -1e30f;
#pragma unroll
        for (int p = 0; p < 49; p++) { ck[p] *= t; m = fmaxf(m, ck[p]); }
        float ssum = 0.f;
#pragma unroll
        for (int p = 0; p < 49; p++) { ck[p] = expf(ck[p] - m); ssum += ck[p]; }
        float inv = 1.f / ssum;
        float sg = sigma[0];
        float dc = 1.f / (2.f * sg * sg);
        float csum = 0.f;
#pragma unroll
        for (int p = 0; p < 49; p++) {
            int dy = p / 7, dx = p % 7;
            float d0 = (dy - 3) / 3.f, d1 = (dx - 3) / 3.f;
            float sp = expf(-(d0 * d0 + d1 * d1) * dc);
            ck[p] = ck[p] * inv * sp;
            csum += ck[p];
        }
        float r = 1.f / fmaxf(csum, 1e-7f);
#pragma unroll
        for (int p = 0; p < 49; p++) ck[p] *= r;
    }
    __syncthreads();  // all reads of proj halo done before lo staging overwrites smem

    // ---- contiguous 22-window covering all reflect-padded taps ----
    int ws_y = y0 - 3; if (ws_y < 0) ws_y = 0; if (ws_y > H - 22) ws_y = H - 22;
    int ws_x = x0 - 3; if (ws_x < 0) ws_x = 0; if (ws_x > W - 22) ws_x = W - 22;
    int ls_y = (ws_y >> 1) - 2, ls_x = (ws_x >> 1) - 2;
    int ry[7], rx[7];
#pragma unroll
    for (int d = 0; d < 7; d++) {
        int v = y0 + ty + d - 3; v = v < 0 ? -v : (v >= H ? 2 * H - 2 - v : v);
        ry[d] = v - ws_y;
        int u = x0 + tx + d - 3; u = u < 0 ? -u : (u >= W ? 2 * W - 2 - u : u);
        rx[d] = u - ws_x;
    }

    // staging coords for lo tile (per-element clamp handles bicubic edge-clamp)
    int lrow = ls_y + ty; lrow = lrow < 0 ? 0 : (lrow >= h ? h - 1 : lrow);
    int lcol = ls_x + tx; lcol = lcol < 0 ? 0 : (lcol >= w ? w - 1 : lcol);

    const int nchunk = (256 / CS) / 8;
    for (int cc = 0; cc < nchunk; cc++) {
        int c0 = c_base + cc * 8;
        // stage lo [8][16][16]
        const float* lp = lo + (((long)b * 256 + c0) * h + lrow) * w + lcol;
#pragma unroll
        for (int c = 0; c < 8; c++)
            lo_s[c * 256 + ty * 16 + tx] = lp[(long)c * h * w];
        __syncthreads();

        // horizontal bicubic: tmp [8][16 lo-rows][22 hr-cols]   (2816 = 11*256)
#pragma unroll
        for (int it = 0; it < 11; it++) {
            int e = tid + it * 256;
            int c = e / 352, r = e % 352;
            int j = r / 22, Xp = r % 22;
            int X = ws_x + Xp;
            int ix = (X >> 1) - ls_x;
            const float* lr = lo_s + c * 256 + j * 16;
            float v;
            if (X & 1)
                v = -0.10546875f * lr[ix - 1] + 0.87890625f * lr[ix] + 0.26171875f * lr[ix + 1] - 0.03515625f * lr[ix + 2];
            else
                v = -0.03515625f * lr[ix - 2] + 0.26171875f * lr[ix - 1] + 0.87890625f * lr[ix] - 0.10546875f * lr[ix + 1];
            tmp_s[c * 368 + j * 23 + Xp] = v;
        }
        __syncthreads();

        // vertical bicubic: hr [8][22][22] (stride 23)   (3872 elems, 16 iters)
#pragma unroll
        for (int it = 0; it < 16; it++) {
            int e = tid + it * 256;
            if (e < 3872) {
                int c = e / 484, r = e % 484;
                int i = r / 22, Xp = r % 22;
                int Y = ws_y + i;
                int jy = (Y >> 1) - ls_y;
                const float* tc = tmp_s + c * 368 + Xp;
                float v;
                if (Y & 1)
                    v = -0.10546875f * tc[(jy - 1) * 23] + 0.87890625f * tc[jy * 23] + 0.26171875f * tc[(jy + 1) * 23] - 0.03515625f * tc[(jy + 2) * 23];
                else
                    v = -0.03515625f * tc[(jy - 2) * 23] + 0.26171875f * tc[(jy - 1) * 23] + 0.87890625f * tc[jy * 23] - 0.10546875f * tc[(jy + 1) * 23];
                hr_s[c * 506 + i * 23 + Xp] = v;
            }
        }
        __syncthreads();

        // apply 49 taps
        float* op = out + (((long)b * 256 + c0) * H + (y0 + ty)) * W + (x0 + tx);
#pragma unroll
        for (int c = 0; c < 8; c++) {
            const float* hc = hr_s + c * 506;
            float acc = 0.f;
#pragma unroll
            for (int dy = 0; dy < 7; dy++) {
                const float* hrow = hc + ry[dy] * 23;
#pragma unroll
                for (int dx = 0; dx < 7; dx++)
                    acc += ck[dy * 7 + dx] * hrow[rx[dx]];
            }
            op[(long)c * H * W] = acc;
        }
        __syncthreads();
    }
}

// ---------------- prep: pack W[o][c] fp32 -> bf16 MFMA A-fragment order ----------------
__global__ void k_prepw(const float* __restrict__ w, unsigned short* __restrict__ wf) {
    int blk = blockIdx.x;           // mt*16+ks, 128 blocks
    int lane = threadIdx.x;         // 64
    int mt = blk >> 4, ks = blk & 15;
    int o = mt * 32 + (lane & 31);
    int c = ks * 16 + (lane >> 5) * 8;
    const float* wp = w + (long)o * 256 + c;
    float4 v0 = *(const float4*)wp;
    float4 v1 = *(const float4*)(wp + 4);
    unsigned short* dst = wf + ((long)(blk * 64 + lane)) * 8;
    unsigned int r0 = f2bf(v0.x) | ((unsigned int)f2bf(v0.y) << 16);
    unsigned int r1 = f2bf(v0.z) | ((unsigned int)f2bf(v0.w) << 16);
    unsigned int r2 = f2bf(v1.x) | ((unsigned int)f2bf(v1.y) << 16);
    unsigned int r3 = f2bf(v1.z) | ((unsigned int)f2bf(v1.w) << 16);
    uint4 pk = {r0, r1, r2, r3};
    *(uint4*)dst = pk;
}

// ---------------- MFMA GEMM: y = W @ x (+ optional GN-fold on x, + optional residual) ----
#define LDK 264
template <bool GN, bool RESID>
__global__ __launch_bounds__(256) void k_gemm256(float* __restrict__ x,
                                                 const unsigned short* __restrict__ wf,
                                                 const float* __restrict__ stats,
                                                 const float* __restrict__ gn_w,
                                                 const float* __restrict__ gn_b) {
    __shared__ unsigned short xs[64 * LDK];
    __shared__ float scl_s[256], sh_s[256];
    int tid = threadIdx.x;
    int b = blockIdx.y;
    int pix0 = blockIdx.x * 64;
    float* xb = x + (long)b * 256 * HW2;

    if (GN) {
        int c = tid;
        int g = c >> 3;
        float mean = stats[(b * 32 + g) * 2];
        float rstd = stats[(b * 32 + g) * 2 + 1];
        float s = rstd * gn_w[c];
        scl_s[c] = s;
        sh_s[c] = gn_b[c] - mean * s;
        __syncthreads();
    }

#pragma unroll
    for (int it = 0; it < 4; it++) {
        int c0 = ((tid >> 4) << 2) + it * 64;
        int px = (tid & 15) << 2;
        const float* gp = xb + (long)c0 * HW2 + pix0 + px;
        float4 v0 = *(const float4*)gp;
        float4 v1 = *(const float4*)(gp + HW2);
        float4 v2 = *(const float4*)(gp + 2 * HW2);
        float4 v3 = *(const float4*)(gp + 3 * HW2);
        if (GN) {
            float s0 = scl_s[c0], h0 = sh_s[c0];
            float s1 = scl_s[c0 + 1], h1 = sh_s[c0 + 1];
            float s2 = scl_s[c0 + 2], h2 = sh_s[c0 + 2];
            float s3 = scl_s[c0 + 3], h3 = sh_s[c0 + 3];
            v0.x = v0.x * s0 + h0; v0.y = v0.y * s0 + h0; v0.z = v0.z * s0 + h0; v0.w = v0.w * s0 + h0;
            v1.x = v1.x * s1 + h1; v1.y = v1.y * s1 + h1; v1.z = v1.z * s1 + h1; v1.w = v1.w * s1 + h1;
            v2.x = v2.x * s2 + h2; v2.y = v2.y * s2 + h2; v2.z = v2.z * s2 + h2; v2.w = v2.w * s2 + h2;
            v3.x = v3.x * s3 + h3; v3.y = v3.y * s3 + h3; v3.z = v3.z * s3 + h3; v3.w = v3.w * s3 + h3;
        }
        float p0[4] = {v0.x, v0.y, v0.z, v0.w};
        float p1[4] = {v1.x, v1.y, v1.z, v1.w};
        float p2[4] = {v2.x, v2.y, v2.z, v2.w};
        float p3[4] = {v3.x, v3.y, v3.z, v3.w};
#pragma unroll
        for (int p = 0; p < 4; p++) {
            ushort4 u;
            u.x = f2bf(p0[p]); u.y = f2bf(p1[p]); u.z = f2bf(p2[p]); u.w = f2bf(p3[p]);
            *(ushort4*)&xs[(px + p) * LDK + c0] = u;
        }
    }
    __syncthreads();

    int lane = tid & 63, wv = tid >> 6;
    fvec16 acc[2][2];
#pragma unroll
    for (int mi = 0; mi < 2; mi++)
#pragma unroll
        for (int ni = 0; ni < 2; ni++)
            acc[mi][ni] = (fvec16)(0.f);

    int n_in = lane & 31;
    int koff = (lane >> 5) * 8;
#pragma unroll
    for (int ks = 0; ks < 16; ks++) {
        s8b a0 = *(const s8b*)(wf + ((long)(((wv * 2 + 0) * 16 + ks) * 64 + lane)) * 8);
        s8b a1 = *(const s8b*)(wf + ((long)(((wv * 2 + 1) * 16 + ks) * 64 + lane)) * 8);
        s8b b0 = *(const s8b*)&xs[(0 + n_in) * LDK + ks * 16 + koff];
        s8b b1 = *(const s8b*)&xs[(32 + n_in) * LDK + ks * 16 + koff];
        acc[0][0] = __builtin_amdgcn_mfma_f32_32x32x16_bf16(a0, b0, acc[0][0], 0, 0, 0);
        acc[0][1] = __builtin_amdgcn_mfma_f32_32x32x16_bf16(a0, b1, acc[0][1], 0, 0, 0);
        acc[1][0] = __builtin_amdgcn_mfma_f32_32x32x16_bf16(a1, b0, acc[1][0], 0, 0, 0);
        acc[1][1] = __builtin_amdgcn_mfma_f32_32x32x16_bf16(a1, b1, acc[1][1], 0, 0, 0);
    }

    int hh = lane >> 5;
#pragma unroll
    for (int mi = 0; mi < 2; mi++) {
        int mt = wv * 2 + mi;
#pragma unroll
        for (int ni = 0; ni < 2; ni++) {
            int pix = pix0 + ni * 32 + n_in;
#pragma unroll
            for (int r = 0; r < 16; r++) {
                int row = (r & 3) + 8 * (r >> 2) + 4 * hh;
                long addr = (long)(mt * 32 + row) * HW2 + pix;
                if (RESID)
                    xb[addr] = xb[addr] + 0.1f * acc[mi][ni][r];
                else
                    xb[addr] = acc[mi][ni][r];
            }
        }
    }
}

// ---------------- GroupNorm stats: 2-pass ----------------
__global__ void k_gnpart(const float* __restrict__ x, double* __restrict__ part) {
    __shared__ double s_s[256], q_s[256];
    int blk = blockIdx.x;
    int bg = blk >> 4, ch = blk & 15;
    const int CHUNK = 8 * HW2 / 16;  // 30720
    const float* xp = x + (long)bg * 8 * HW2 + (long)ch * CHUNK;
    double s = 0.0, q = 0.0;
    for (int i = threadIdx.x; i < CHUNK; i += 256) {
        float v = xp[i];
        s += v; q += (double)v * v;
    }
    s_s[threadIdx.x] = s; q_s[threadIdx.x] = q;
    __syncthreads();
    for (int st = 128; st > 0; st >>= 1) {
        if (threadIdx.x < st) { s_s[threadIdx.x] += s_s[threadIdx.x + st]; q_s[threadIdx.x] += q_s[threadIdx.x + st]; }
        __syncthreads();
    }
    if (threadIdx.x == 0) {
        part[blk * 2] = s_s[0];
        part[blk * 2 + 1] = q_s[0];
    }
}

__global__ void k_gnred(const double* __restrict__ part, float* __restrict__ stats) {
    int bg = threadIdx.x;  // 64
    double s = 0.0, q = 0.0;
    for (int ch = 0; ch < 16; ch++) {
        s += part[(bg * 16 + ch) * 2];
        q += part[(bg * 16 + ch) * 2 + 1];
    }
    double N = 8.0 * HW2;
    double mean = s / N;
    double var = q / N - mean * mean;
    stats[bg * 2] = (float)mean;
    stats[bg * 2 + 1] = (float)(1.0 / sqrt(var + 1e-5));
}

extern "C" void kernel_launch(void* const* d_in, const int* in_sizes, int n_in,
                              void* d_out, int out_size, void* d_ws, size_t ws_size,
                              hipStream_t stream) {
    const float* src      = (const float*)d_in[0];
    const float* guidance = (const float*)d_in[1];
    const float* pre_w    = (const float*)d_in[2];
    const float* rp1_w1   = (const float*)d_in[3];
    const float* rp1_b1   = (const float*)d_in[4];
    const float* rp1_w2   = (const float*)d_in[5];
    const float* rp1_b2   = (const float*)d_in[6];
    const float* temp1    = (const float*)d_in[7];
    const float* sigma1   = (const float*)d_in[8];
    const float* rp2_w1   = (const float*)d_in[9];
    const float* rp2_b1   = (const float*)d_in[10];
    const float* rp2_w2   = (const float*)d_in[11];
    const float* rp2_b2   = (const float*)d_in[12];
    const float* temp2    = (const float*)d_in[13];
    const float* sigma2   = (const float*)d_in[14];
    const float* fixup_w  = (const float*)d_in[15];
    const float* gn_w     = (const float*)d_in[16];
    const float* gn_b     = (const float*)d_in[17];
    const float* proj_w   = (const float*)d_in[18];
    float* out = (float*)d_out;

    // ---- workspace arena ----
    char* ws = (char*)d_ws;
    size_t off = 0;
    auto alloc = [&](size_t bytes) { size_t o = off; off = (off + bytes + 255) & ~(size_t)255; return o; };
    float* gdown  = (float*)(ws + alloc((size_t)2 * 3 * 192 * 1280 * 4));
    float* gbuf   = (float*)(ws + alloc((size_t)2 * 3 * 192 * 320 * 4));
    float* projb  = (float*)(ws + alloc((size_t)2 * 32 * 192 * 320 * 4));
    float* x1     = (float*)(ws + alloc((size_t)2 * 256 * 48 * 80 * 4));
    float* out1   = (float*)(ws + alloc((size_t)2 * 256 * 96 * 160 * 4));
    unsigned short* wfFix  = (unsigned short*)(ws + alloc(65536 * 2));
    unsigned short* wfProj = (unsigned short*)(ws + alloc(65536 * 2));
    double* gpart = (double*)(ws + alloc(1024 * 2 * 8));
    float* stats  = (float*)(ws + alloc(64 * 2 * 4));

    // weight prep (bf16 MFMA fragment order)
    k_prepw<<<128, 64, 0, stream>>>(fixup_w, wfFix);
    k_prepw<<<128, 64, 0, stream>>>(proj_w, wfProj);

    // pre-projection 384->256
    k_preproj<<<512, 256, 0, stream>>>(src, pre_w, x1);

    // ---- JBU step 1: 48x80 -> 96x160 (fused ck+bicubic+apply, 2-way channel split) ----
    {
        const int H = 96, W = 160, HW = H * W;
        k_down_h<<<(2 * 3 * H * 1280) / 256, 256, 0, stream>>>(guidance, gdown, H, 8.f);
        k_down_w<<<(2 * 3 * HW + 255) / 256, 256, 0, stream>>>(gdown, gbuf, H, W, 8.f);
        k_proj<<<(2 * HW + 255) / 256, 256, 0, stream>>>(gbuf, projb, rp1_w1, rp1_b1, rp1_w2, rp1_b2, HW);
        k_fused<2><<<dim3(W / 16, H / 16, 2 * 2), 256, 0, stream>>>(x1, projb, out1, temp1, sigma1, H, W, 48, 80);
    }

    // ---- JBU step 2: 96x160 -> 192x320 ----
    {
        const int H = 192, W = 320, HW = H * W;
        k_down_h<<<(2 * 3 * H * 1280) / 256, 256, 0, stream>>>(guidance, gdown, H, 4.f);
        k_down_w<<<(2 * 3 * HW + 255) / 256, 256, 0, stream>>>(gdown, gbuf, H, W, 4.f);
        k_proj<<<(2 * HW + 255) / 256, 256, 0, stream>>>(gbuf, projb, rp2_w1, rp2_b1, rp2_w2, rp2_b2, HW);
        k_fused<1><<<dim3(W / 16, H / 16, 2), 256, 0, stream>>>(out1, projb, out, temp2, sigma2, H, W, 96, 160);
    }

    // ---- fixup residual: out = out + 0.1 * W @ out (MFMA, in-place) ----
    k_gemm256<false, true><<<dim3(960, 2), 256, 0, stream>>>(out, wfFix, nullptr, nullptr, nullptr);
    // ---- GroupNorm stats (2-pass) ----
    k_gnpart<<<1024, 256, 0, stream>>>(out, gpart);
    k_gnred<<<1, 64, 0, stream>>>(gpart, stats);
    // ---- GN affine + final projection (MFMA, in-place) ----
    k_gemm256<true, false><<<dim3(960, 2), 256, 0, stream>>>(out, wfProj, stats, gn_w, gn_b);
}